// Round 3
// baseline (270.263 us; speedup 1.0000x reference)
//
#include <hip/hip_runtime.h>

#define NUM_NODES 20000
#define NUM_EDGES 640000
#define DIM 128
#define NUM_HEADS 8
#define HEAD_DIM 16
#define NEG_SLOPE 0.01f

typedef __attribute__((ext_vector_type(4))) float float4v;

// Order-preserving float <-> uint mapping for atomicMax on signed floats.
__device__ __forceinline__ unsigned f2o(float f) {
    unsigned u = __float_as_uint(f);
    return (u & 0x80000000u) ? ~u : (u | 0x80000000u);
}
__device__ __forceinline__ float o2f(unsigned u) {
    return (u & 0x80000000u) ? __uint_as_float(u & 0x7FFFFFFFu)
                             : __uint_as_float(~u);
}

// edge_index may be int32 (harness contract) or int64 (reference dtype).
// Detector: for int64 (little-endian, values < 2^31), every odd 32-bit word
// is zero. For int32, odd words are edge ids in [0,20000) — P(all 256 zero)~0.
// flag != 0  =>  int32 layout.
__global__ void k_detect(const unsigned* __restrict__ ei_raw, int* __restrict__ flag) {
    if (ei_raw[2 * threadIdx.x + 1] != 0) atomicOr(flag, 1);
}

__device__ __forceinline__ int get_target(const int* __restrict__ ei, int e, int is32) {
    return is32 ? ei[NUM_EDGES + e] : ei[2 * (NUM_EDGES + e)];
}

// K1: per-(edge,head): load f32 msg/x_t slices, fused bit-exact msg copy,
// dot with weight, LeakyReLU, store f32 score, atomic segment-max.
__global__ __launch_bounds__(256) void k_score(
    const int* __restrict__ ei,
    const float* __restrict__ msg,         // (E, 128) f32
    const float* __restrict__ xe,          // (N, 128) f32
    const float* __restrict__ wt,          // (8, 32) f32
    float* __restrict__ out_msg,           // (E, 128) f32
    float* __restrict__ scores,            // (E, 8) f32 ws
    unsigned* __restrict__ seg_max,        // (N, 8) ordered-uint ws
    const int* __restrict__ flag)
{
    __shared__ float w[NUM_HEADS * 2 * HEAD_DIM];  // 256 floats
    const int tid = threadIdx.x;
    w[tid] = wt[tid];
    __syncthreads();

    const int gid = blockIdx.x * 256 + tid;  // exact: 20000*256 == E*H
    const int h = gid & 7;
    const int e = gid >> 3;

    const int t = get_target(ei, e, *flag);

    const float* mp = msg + (size_t)e * DIM + h * HEAD_DIM;
    const float* xp = xe + (size_t)t * DIM + h * HEAD_DIM;

    float4v m[4], x[4];
#pragma unroll
    for (int i = 0; i < 4; i++) m[i] = *(const float4v*)(mp + 4 * i);
#pragma unroll
    for (int i = 0; i < 4; i++) x[i] = *(const float4v*)(xp + 4 * i);

    // Bit-exact fused copy of message -> output 0 (64 B/thread, coalesced).
    float* op = out_msg + (size_t)e * DIM + h * HEAD_DIM;
#pragma unroll
    for (int i = 0; i < 4; i++) *(float4v*)(op + 4 * i) = m[i];

    const float* wh = w + h * (2 * HEAD_DIM);
    float s = 0.f;
#pragma unroll
    for (int i = 0; i < 4; i++)
#pragma unroll
        for (int j = 0; j < 4; j++) {
            s += m[i][j] * wh[i * 4 + j];
            s += x[i][j] * wh[16 + i * 4 + j];
        }

    s = (s >= 0.f) ? s : NEG_SLOPE * s;  // LeakyReLU

    scores[gid] = s;
    atomicMax(&seg_max[t * NUM_HEADS + h], f2o(s));
}

// K2: exp(score - segmax) -> atomic segment sum.
__global__ __launch_bounds__(256) void k_sum(
    const int* __restrict__ ei,
    const float* __restrict__ scores,
    const unsigned* __restrict__ seg_max,
    float* __restrict__ seg_sum,
    const int* __restrict__ flag)
{
    const int gid = blockIdx.x * 256 + threadIdx.x;
    const int h = gid & 7;
    const int e = gid >> 3;

    const int t = get_target(ei, e, *flag);
    const float m = o2f(seg_max[t * NUM_HEADS + h]);
    atomicAdd(&seg_sum[t * NUM_HEADS + h], __expf(scores[gid] - m));
}

// K3: recompute exp, normalize, emit f32 alpha.
__global__ __launch_bounds__(256) void k_div(
    const int* __restrict__ ei,
    const float* __restrict__ scores,
    const unsigned* __restrict__ seg_max,
    const float* __restrict__ seg_sum,
    float* __restrict__ out_alpha,
    const int* __restrict__ flag)
{
    const int gid = blockIdx.x * 256 + threadIdx.x;
    const int h = gid & 7;
    const int e = gid >> 3;

    const int t = get_target(ei, e, *flag);
    const int k = t * NUM_HEADS + h;
    const float ex = __expf(scores[gid] - o2f(seg_max[k]));
    out_alpha[gid] = ex / (seg_sum[k] + 1e-16f);
}

extern "C" void kernel_launch(void* const* d_in, const int* in_sizes, int n_in,
                              void* d_out, int out_size, void* d_ws, size_t ws_size,
                              hipStream_t stream) {
    const int* ei = (const int*)d_in[0];
    const float* msg = (const float*)d_in[1];
    const float* xe = (const float*)d_in[2];
    const float* wt = (const float*)d_in[3];

    float* out_msg = (float*)d_out;                             // (E,128) f32
    float* out_alpha = out_msg + (size_t)NUM_EDGES * DIM;       // (E,8) f32

    char* ws = (char*)d_ws;
    float* scores = (float*)ws;                                 // E*8 f32 = 20.48 MB
    size_t off = (size_t)NUM_EDGES * NUM_HEADS * sizeof(float);
    unsigned* seg_max = (unsigned*)(ws + off);                  // N*8 u32
    float* seg_sum = (float*)(ws + off + (size_t)NUM_NODES * NUM_HEADS * 4);
    int* flag = (int*)(ws + off + (size_t)NUM_NODES * NUM_HEADS * 8);

    // Zero seg_max (ordered-uint 0 < any mapped finite float), seg_sum, flag.
    hipMemsetAsync(seg_max, 0, (size_t)NUM_NODES * NUM_HEADS * 8 + 4, stream);

    const int blocks = NUM_EDGES * NUM_HEADS / 256;  // 20,000 exact

    k_detect<<<1, 256, 0, stream>>>((const unsigned*)ei, flag);
    k_score<<<blocks, 256, 0, stream>>>(ei, msg, xe, wt, out_msg, scores, seg_max, flag);
    k_sum<<<blocks, 256, 0, stream>>>(ei, scores, seg_max, seg_sum, flag);
    k_div<<<blocks, 256, 0, stream>>>(ei, scores, seg_max, seg_sum, out_alpha, flag);
}